// Round 9
// baseline (375.817 us; speedup 1.0000x reference)
//
#include <hip/hip_runtime.h>
#include <hip/hip_bf16.h>

// Attention_4363686773373: sigmoid attention block, all-bf16 MFMA pipeline.
// B=4 T=2048 D=768 H=12 HD=64.  Output fp32.
// R9: GEMMs -> prefetch distance 2 (two register sets, x2-unrolled loop:
// load latency ~900cyc > 1x compute ~250cyc caused per-iter vmcnt stalls;
// 2 iters of cover ~600+cyc). attn reverted to R5 exact (77.7us, 0 conflicts,
// best of R5-R8 structural sweep — dependency-chain floor). vT pi-permuted.

typedef __bf16 bf16_t;
typedef __bf16 bf16x8 __attribute__((ext_vector_type(8)));
typedef __bf16 bf16x4 __attribute__((ext_vector_type(4)));
typedef float floatx4 __attribute__((ext_vector_type(4)));

#define MFMA16x16x32(a, b, c) __builtin_amdgcn_mfma_f32_16x16x32_bf16((a), (b), (c), 0, 0, 0)

static constexpr float kEPS  = 1e-4f;
static constexpr float kGAIN = 1.8402f;
static constexpr float kC    = -0.18033688011112042f;   // -0.125 * log2(e)

// ---------------------------------------------------------------------------
// 1) merged preprocessing:
//    blocks [0,3072): row-normalize [qkv_w ; out_w] rows -> bf16
//    blocks [3072,11264): x -> bf16 + per-token magnitude ||x||/sqrt(D)
// ---------------------------------------------------------------------------
__global__ __launch_bounds__(256) void prep_kernel(const float* __restrict__ x,
                                                   const float* __restrict__ qkv_w,
                                                   const float* __restrict__ out_w,
                                                   bf16_t* __restrict__ wn_all,
                                                   bf16_t* __restrict__ xb,
                                                   float* __restrict__ mag) {
    __shared__ float red[4];
    int b = blockIdx.x;
    if (b < 3072) {
        const float* wr = (b < 2304) ? qkv_w + (size_t)b * 768
                                     : out_w + (size_t)(b - 2304) * 768;
        float ss = 0.f;
        for (int c = threadIdx.x; c < 768; c += 256) { float v = wr[c]; ss += v * v; }
        for (int m = 32; m; m >>= 1) ss += __shfl_xor(ss, m, 64);
        if ((threadIdx.x & 63) == 0) red[threadIdx.x >> 6] = ss;
        __syncthreads();
        float inv = 1.0f / (sqrtf(red[0] + red[1] + red[2] + red[3]) + kEPS);
        bf16_t* wo = wn_all + (size_t)b * 768;
        for (int c = threadIdx.x; c < 768; c += 256) wo[c] = (bf16_t)(wr[c] * inv);
    } else {
        int tok = b - 3072;               // 0..8191
        const float* xr = x + (size_t)tok * 768;
        float ss = 0.f;
        for (int c = threadIdx.x; c < 768; c += 256) { float v = xr[c]; ss += v * v; }
        for (int m = 32; m; m >>= 1) ss += __shfl_xor(ss, m, 64);
        if ((threadIdx.x & 63) == 0) red[threadIdx.x >> 6] = ss;
        __syncthreads();
        float tot = red[0] + red[1] + red[2] + red[3];
        if (threadIdx.x == 0) mag[tok] = sqrtf(tot) * 0.036084391824352f;  // 1/sqrt(768)
        bf16_t* xo = xb + (size_t)tok * 768;
        for (int c = threadIdx.x; c < 768; c += 256) xo[c] = (bf16_t)xr[c];
    }
}

// ---------------------------------------------------------------------------
// 3) GEMM1: qkv = xb(8192x768) @ wn^T(2304x768).  128x128 tile, BK=32,
//    distance-2 register prefetch (x2-unrolled: set index compile-time).
//    Lane-order LDS (stores lane-consecutive 16B). Epilogue: q/k per-head
//    normalize (q also *kC) -> qkvh; v (p==2) transposed via LDS to vT
//    (pi-permuted columns).
// ---------------------------------------------------------------------------
__global__ __launch_bounds__(256) void gemm_qkv_kernel(const bf16_t* __restrict__ A,
                                                       const bf16_t* __restrict__ Bw,
                                                       bf16_t* __restrict__ qkvh,
                                                       bf16_t* __restrict__ vT) {
    __shared__ __align__(16) bf16_t sm[8704];   // As 4096 | Bs 4096; reused 64x136 for v-transpose
    bf16_t* As = sm;
    bf16_t* Bs = sm + 4096;

    const int m0 = blockIdx.x * 128;
    const int n0 = blockIdx.y * 128;
    const int tid = threadIdx.x;
    const int wave = tid >> 6, lane = tid & 63;
    const int quad = lane >> 4, l16 = lane & 15;
    const int wr = (wave >> 1) * 64, wc = (wave & 1) * 64;
    const int srow = lane & 15, schunk = lane >> 4;   // staging lane map

    floatx4 acc[4][4];
    for (int i = 0; i < 4; i++)
        for (int j = 0; j < 4; j++) acc[i][j] = (floatx4){0.f, 0.f, 0.f, 0.f};

    const bf16_t* aptr0 = A  + (size_t)(m0 + wave * 32 + srow) * 768 + schunk * 8;
    const bf16_t* bptr0 = Bw + (size_t)(n0 + wave * 32 + srow) * 768 + schunk * 8;
    const int abase = wave * 1024;                    // per-wave region: 2 x 512

    uint4 ar0[2], ar1[2], br0[2], br1[2];             // two prefetch sets

#define GQ_ISSUE(SET, K0)                                                  \
    {                                                                      \
        ar0[SET] = *(const uint4*)(aptr0 + (K0));                          \
        ar1[SET] = *(const uint4*)(aptr0 + (K0) + 16 * 768);               \
        br0[SET] = *(const uint4*)(bptr0 + (K0));                          \
        br1[SET] = *(const uint4*)(bptr0 + (K0) + 16 * 768);               \
    }

    GQ_ISSUE(0, 0)
    GQ_ISSUE(1, 32)

    auto compute = [&]() {
        bf16x8 af[4], bfr[4];
#pragma unroll
        for (int i = 0; i < 4; i++)
            af[i] = *(const bf16x8*)&As[((wr >> 4) + i) * 512 + quad * 128 + l16 * 8];
#pragma unroll
        for (int j = 0; j < 4; j++)
            bfr[j] = *(const bf16x8*)&Bs[((wc >> 4) + j) * 512 + quad * 128 + l16 * 8];
#pragma unroll
        for (int i = 0; i < 4; i++)
#pragma unroll
            for (int j = 0; j < 4; j++) acc[i][j] = MFMA16x16x32(af[i], bfr[j], acc[i][j]);
    };

#define GQ_STEP(SET, IT)                                                   \
    {                                                                      \
        __syncthreads();                                                   \
        *(uint4*)&As[abase + lane * 8]       = ar0[SET];                   \
        *(uint4*)&As[abase + 512 + lane * 8] = ar1[SET];                   \
        *(uint4*)&Bs[abase + lane * 8]       = br0[SET];                   \
        *(uint4*)&Bs[abase + 512 + lane * 8] = br1[SET];                   \
        if ((IT) + 2 < 24) GQ_ISSUE(SET, ((IT) + 2) * 32)                  \
        __syncthreads();                                                   \
        compute();                                                         \
    }

    for (int it = 0; it < 24; it += 2) {
        GQ_STEP(0, it)
        GQ_STEP(1, it + 1)
    }
#undef GQ_STEP
#undef GQ_ISSUE

    const int p = n0 / 768;        // block-uniform (768 % 128 == 0)
    const int bat = m0 >> 11, t0 = m0 & 2047;

    if (p < 2) {
        // ---- q/k: fused per-head normalize, scatter to qkvh ----
        const int h = ((n0 + wc) - p * 768) >> 6;
        const float base = (p == 0) ? kC * 8.0f : 8.0f;
        for (int i = 0; i < 4; i++)
            for (int r = 0; r < 4; r++) {
                float vals[4], ss = 0.f;
                for (int j = 0; j < 4; j++) { float v = acc[i][j][r]; vals[j] = v; ss += v * v; }
                ss += __shfl_xor(ss, 1, 64);
                ss += __shfl_xor(ss, 2, 64);
                ss += __shfl_xor(ss, 4, 64);
                ss += __shfl_xor(ss, 8, 64);
                float scale = base / (sqrtf(ss) + kEPS);
                int m = m0 + wr + i * 16 + quad * 4 + r;
                int t = m & 2047;
                bf16_t* dst = qkvh + ((((size_t)p * 4 + bat) * 12 + h) * 2048 + t) * 64;
                for (int j = 0; j < 4; j++) dst[j * 16 + l16] = (bf16_t)(vals[j] * scale);
            }
    } else {
        // ---- v: transpose via LDS, write vT[(bh)*64+d][t] pi-permuted ----
        __syncthreads();                         // everyone done with As/Bs
        const int h0 = (n0 - 1536) >> 6;         // block head base (2 heads/block)
        for (int hh = 0; hh < 2; hh++) {
            if ((wc >> 6) == hh) {
                for (int i = 0; i < 4; i++)
                    for (int r = 0; r < 4; r++) {
                        int tl = wr + i * 16 + quad * 4 + r;
                        for (int j = 0; j < 4; j++)
                            sm[(j * 16 + l16) * 136 + tl] = (bf16_t)acc[i][j][r];
                    }
            }
            __syncthreads();
            bf16_t* dst = vT + ((size_t)(bat * 12 + h0 + hh) * 64) * 2048 + t0;
            for (int u = tid; u < 1024; u += 256) {
                int d = u >> 4, c = u & 15;
                bf16_t tmp[8];
#pragma unroll
                for (int q = 0; q < 8; q++) {
                    int sp = c * 8 + q;                      // out position 0..127
                    int q6 = sp & 63;
                    int tl = (sp & 64) + ((q6 & 3) << 4) + (q6 >> 2);   // pi_inv
                    tmp[q] = sm[d * 136 + tl];
                }
                *(uint4*)&dst[(size_t)d * 2048 + c * 8] = *(uint4*)tmp;
            }
            __syncthreads();
        }
    }
}

// ---------------------------------------------------------------------------
// 6) sigmoid attention, fused per-head output normalize + mag rescale.
//    grid (48, 16): x = head (XCD-affine), y = q-tile. 512 thr = 8 waves x
//    16 q-rows. s-tile 64, dbuf K/V, one barrier per s-tile. (R5 exact —
//    best of the R5-R8 structural sweep; dependency-chain floor ~77us.)
// ---------------------------------------------------------------------------
__global__ __launch_bounds__(512, 6) void attn_kernel(const bf16_t* __restrict__ qkvh,
                                                      const bf16_t* __restrict__ vT,
                                                      const float* __restrict__ mag,
                                                      bf16_t* __restrict__ y) {
    __shared__ bf16_t QP[128 * 64];          // Q tile, then reused as Ps
    __shared__ bf16_t KV[2][2][64 * 64];     // [buf][0=K,1=V(pi-order)]

    const int bh = blockIdx.x, bat = bh / 12, h = bh % 12;
    const int m0 = blockIdx.y * 128;
    const bf16_t* qbase = qkvh + (((size_t)bat * 12 + h) * 2048) * 64;            // p=0
    const bf16_t* kbase = qkvh + (((size_t)(4 + bat) * 12 + h) * 2048) * 64;      // p=1
    const bf16_t* vbase = vT + ((size_t)bh * 64) * 2048;

    const int tid = threadIdx.x, wave = tid >> 6, lane = tid & 63;
    const int quad = lane >> 4, l16 = lane & 15;

    // ---- stage Q (swizzled): 1024 uint4 over 512 threads ----
    for (int s = tid; s < 1024; s += 512) {
        int r = s >> 3, blk = s & 7;
        *(uint4*)&QP[r * 64 + ((blk ^ (r & 7)) * 8)] =
            *(const uint4*)&qbase[(size_t)(m0 + r) * 64 + blk * 8];
    }

    // ---- K/V prefetch (1 uint4 of each per thread) ----
    uint4 kr, vr;
    const int slr = tid >> 3, slb = tid & 7;
    auto issue = [&](int s0) {
        kr = *(const uint4*)&kbase[(size_t)(s0 + slr) * 64 + slb * 8];
        vr = *(const uint4*)&vbase[(size_t)slr * 2048 + s0 + slb * 8];
    };
    const int sw = ((slb ^ (slr & 7)) * 8);
    auto commit = [&](int buf) {
        *(uint4*)&KV[buf][0][slr * 64 + sw] = kr;
        *(uint4*)&KV[buf][1][slr * 64 + sw] = vr;
    };

    issue(0);
    __syncthreads();   // Q staged

    // ---- Q fragments -> registers (wave-private rows; QP freed for Ps) ----
    const int qrow = wave * 16 + l16;
    bf16x8 qf0 = *(const bf16x8*)&QP[qrow * 64 + ((quad ^ (l16 & 7)) * 8)];
    bf16x8 qf1 = *(const bf16x8*)&QP[qrow * 64 + (((4 + quad) ^ (l16 & 7)) * 8)];

    commit(0);
    issue(64);
    __syncthreads();   // KV[0] visible; all qf reads done before Ps writes

    floatx4 o[4];
#pragma unroll
    for (int j = 0; j < 4; j++) o[j] = (floatx4){0.f, 0.f, 0.f, 0.f};

    for (int it = 0; it < 32; ++it) {
        const bf16_t* Ks = KV[it & 1][0];
        const bf16_t* Vt = KV[it & 1][1];
        if (it < 31) {
            commit((it + 1) & 1);        // regs loaded one iter ago
            if (it < 30) issue((it + 2) * 64);
        }

        // ---- S = Q.K^T (16 q-rows x 64 s per wave) ----
        floatx4 sacc[4];
#pragma unroll
        for (int j = 0; j < 4; j++) sacc[j] = (floatx4){0.f, 0.f, 0.f, 0.f};
#pragma unroll
        for (int j = 0; j < 4; j++) {
            int row = j * 16 + l16;
            bf16x8 b0 = *(const bf16x8*)&Ks[row * 64 + ((quad ^ (l16 & 7)) * 8)];
            bf16x8 b1 = *(const bf16x8*)&Ks[row * 64 + (((4 + quad) ^ (l16 & 7)) * 8)];
            sacc[j] = MFMA16x16x32(qf0, b0, sacc[j]);
            sacc[j] = MFMA16x16x32(qf1, b1, sacc[j]);
        }

        // ---- sigmoid = rcp(1+exp2(S)) (kC pre-folded into q) -> Ps ----
#pragma unroll
        for (int r = 0; r < 4; r++) {
            int row = wave * 16 + quad * 4 + r;
            bf16x4 pk;
#pragma unroll
            for (int j = 0; j < 4; j++) {
                float t = __builtin_amdgcn_exp2f(sacc[j][r]);
                pk[j] = (bf16_t)__builtin_amdgcn_rcpf(1.0f + t);
            }
            *(bf16x4*)&QP[row * 64 + (((l16 >> 1) ^ (row & 7)) * 8) + (l16 & 1) * 4] = pk;
        }

        // ---- O += P.V (A from QP, B from Vt, both pi-order) ----
        const int prow = wave * 16 + l16;
        bf16x8 af0 = *(const bf16x8*)&QP[prow * 64 + ((quad ^ (l16 & 7)) * 8)];
        bf16x8 af1 = *(const bf16x8*)&QP[prow * 64 + (((4 + quad) ^ (l16 & 7)) * 8)];
#pragma unroll
        for (int j = 0; j < 4; j++) {
            int row = j * 16 + l16;
            bf16x8 b0 = *(const bf16x8*)&Vt[row * 64 + ((quad ^ (l16 & 7)) * 8)];
            bf16x8 b1 = *(const bf16x8*)&Vt[row * 64 + (((4 + quad) ^ (l16 & 7)) * 8)];
            o[j] = MFMA16x16x32(af0, b0, o[j]);
            o[j] = MFMA16x16x32(af1, b1, o[j]);
        }
        __syncthreads();   // one barrier per s-tile
    }

    // ---- epilogue: out = mag * 8 * (kGAIN/sqrt(T)) * o / (||...|| + eps) ----
    const float kfac = kGAIN * 0.02209708691207961f;  // 1.8402/sqrt(2048)
#pragma unroll
    for (int r = 0; r < 4; r++) {
        int t = m0 + wave * 16 + quad * 4 + r;
        float vals[4];
        float ss = 0.f;
#pragma unroll
        for (int j = 0; j < 4; j++) {
            float v = o[j][r] * kfac;
            vals[j] = v;
            ss += v * v;
        }
        for (int msk = 1; msk < 16; msk <<= 1) ss += __shfl_xor(ss, msk, 64);
        float mg = mag[bat * 2048 + t];
        float sc = mg * 8.0f / (sqrtf(ss) + kEPS);
#pragma unroll
        for (int j = 0; j < 4; j++) {
            int d = j * 16 + l16;
            y[((size_t)(bat * 2048 + t)) * 768 + h * 64 + d] = (bf16_t)(vals[j] * sc);
        }
    }
}

// ---------------------------------------------------------------------------
// 7) GEMM2: out = y(8192x768) @ ow^T(768x768) -> fp32, BK=32, distance-2
// ---------------------------------------------------------------------------
__global__ __launch_bounds__(256) void gemm_out_kernel(const bf16_t* __restrict__ A,
                                                       const bf16_t* __restrict__ Bw,
                                                       float* __restrict__ out) {
    __shared__ __align__(16) bf16_t sm[8192];
    bf16_t* As = sm;
    bf16_t* Bs = sm + 4096;

    const int m0 = blockIdx.x * 128;
    const int n0 = blockIdx.y * 128;
    const int tid = threadIdx.x;
    const int wave = tid >> 6, lane = tid & 63;
    const int quad = lane >> 4, l16 = lane & 15;
    const int wr = (wave >> 1) * 64, wc = (wave & 1) * 64;
    const int srow = lane & 15, schunk = lane >> 4;

    floatx4 acc[4][4];
    for (int i = 0; i < 4; i++)
        for (int j = 0; j < 4; j++) acc[i][j] = (floatx4){0.f, 0.f, 0.f, 0.f};

    const bf16_t* aptr0 = A  + (size_t)(m0 + wave * 32 + srow) * 768 + schunk * 8;
    const bf16_t* bptr0 = Bw + (size_t)(n0 + wave * 32 + srow) * 768 + schunk * 8;
    const int abase = wave * 1024;

    uint4 ar0[2], ar1[2], br0[2], br1[2];

#define GO_ISSUE(SET, K0)                                                  \
    {                                                                      \
        ar0[SET] = *(const uint4*)(aptr0 + (K0));                          \
        ar1[SET] = *(const uint4*)(aptr0 + (K0) + 16 * 768);               \
        br0[SET] = *(const uint4*)(bptr0 + (K0));                          \
        br1[SET] = *(const uint4*)(bptr0 + (K0) + 16 * 768);               \
    }

    GO_ISSUE(0, 0)
    GO_ISSUE(1, 32)

    auto compute = [&]() {
        bf16x8 af[4], bfr[4];
#pragma unroll
        for (int i = 0; i < 4; i++)
            af[i] = *(const bf16x8*)&As[((wr >> 4) + i) * 512 + quad * 128 + l16 * 8];
#pragma unroll
        for (int j = 0; j < 4; j++)
            bfr[j] = *(const bf16x8*)&Bs[((wc >> 4) + j) * 512 + quad * 128 + l16 * 8];
#pragma unroll
        for (int i = 0; i < 4; i++)
#pragma unroll
            for (int j = 0; j < 4; j++) acc[i][j] = MFMA16x16x32(af[i], bfr[j], acc[i][j]);
    };

#define GO_STEP(SET, IT)                                                   \
    {                                                                      \
        __syncthreads();                                                   \
        *(uint4*)&As[abase + lane * 8]       = ar0[SET];                   \
        *(uint4*)&As[abase + 512 + lane * 8] = ar1[SET];                   \
        *(uint4*)&Bs[abase + lane * 8]       = br0[SET];                   \
        *(uint4*)&Bs[abase + 512 + lane * 8] = br1[SET];                   \
        if ((IT) + 2 < 24) GO_ISSUE(SET, ((IT) + 2) * 32)                  \
        __syncthreads();                                                   \
        compute();                                                         \
    }

    for (int it = 0; it < 24; it += 2) {
        GO_STEP(0, it)
        GO_STEP(1, it + 1)
    }
#undef GO_STEP
#undef GO_ISSUE

    for (int i = 0; i < 4; i++)
        for (int j = 0; j < 4; j++) {
            int n = n0 + wc + j * 16 + l16;
            for (int r = 0; r < 4; r++) {
                int m = m0 + wr + i * 16 + quad * 4 + r;
                out[(size_t)m * 768 + n] = acc[i][j][r];
            }
        }
}

// ---------------------------------------------------------------------------
extern "C" void kernel_launch(void* const* d_in, const int* in_sizes, int n_in,
                              void* d_out, int out_size, void* d_ws, size_t ws_size,
                              hipStream_t stream) {
    const float* x     = (const float*)d_in[0];   // (4,2048,768)
    const float* qkv_w = (const float*)d_in[1];   // (2304,768)
    const float* out_w = (const float*)d_in[2];   // (768,768)
    float* out = (float*)d_out;

    char* ws = (char*)d_ws;
    bf16_t* wn_all = (bf16_t*)(ws + 0);          //  4,718,592  (3072x768 bf16: qkv_w rows then out_w rows)
    bf16_t* xb     = (bf16_t*)(ws + 4718592);    // 12,582,912  (8192x768 bf16)
    float*  mag    = (float*) (ws + 17301504);   //     32,768  (8192 fp32)
    bf16_t* qkvh   = (bf16_t*)(ws + 17334272);   // 25,165,824  (2x4x12x2048x64 bf16: q,k)
    bf16_t* vT     = (bf16_t*)(ws + 42500096);   // 12,582,912  (48x64x2048 bf16, pi-permuted cols)
    bf16_t* y      = (bf16_t*)(ws + 55083008);   // 12,582,912  (8192x768 bf16)
    // total 67,665,920 bytes

    bf16_t* ow = wn_all + (size_t)2304 * 768;

    prep_kernel<<<11264, 256, 0, stream>>>(x, qkv_w, out_w, wn_all, xb, mag);
    gemm_qkv_kernel<<<dim3(64, 18), 256, 0, stream>>>(xb, wn_all, qkvh, vT);
    attn_kernel<<<dim3(48, 16), 512, 0, stream>>>(qkvh, vT, mag, y);
    gemm_out_kernel<<<dim3(64, 6), 256, 0, stream>>>(y, ow, out);
}

// Round 10
// 241.555 us; speedup vs baseline: 1.5558x; 1.5558x over previous
//
#include <hip/hip_runtime.h>
#include <hip/hip_bf16.h>

// Attention_4363686773373: sigmoid attention block, all-bf16 MFMA pipeline.
// B=4 T=2048 D=768 H=12 HD=64.  Output fp32.
// R10: R5-exact pipeline + GEMMs with distance-2 prefetch done right:
// NAMED uint4 registers (R9's array version spilled to scratch: WRITE_SIZE
// 37->308MB at pinned VGPR=92) and __launch_bounds__(256,2) so the allocator
// may use ~128 VGPRs. attn = R5 exact (77.7us dependency-chain floor).

typedef __bf16 bf16_t;
typedef __bf16 bf16x8 __attribute__((ext_vector_type(8)));
typedef __bf16 bf16x4 __attribute__((ext_vector_type(4)));
typedef float floatx4 __attribute__((ext_vector_type(4)));

#define MFMA16x16x32(a, b, c) __builtin_amdgcn_mfma_f32_16x16x32_bf16((a), (b), (c), 0, 0, 0)

static constexpr float kEPS  = 1e-4f;
static constexpr float kGAIN = 1.8402f;
static constexpr float kC    = -0.18033688011112042f;   // -0.125 * log2(e)

// ---------------------------------------------------------------------------
// 1) merged preprocessing:
//    blocks [0,3072): row-normalize [qkv_w ; out_w] rows -> bf16
//    blocks [3072,11264): x -> bf16 + per-token magnitude ||x||/sqrt(D)
// ---------------------------------------------------------------------------
__global__ __launch_bounds__(256) void prep_kernel(const float* __restrict__ x,
                                                   const float* __restrict__ qkv_w,
                                                   const float* __restrict__ out_w,
                                                   bf16_t* __restrict__ wn_all,
                                                   bf16_t* __restrict__ xb,
                                                   float* __restrict__ mag) {
    __shared__ float red[4];
    int b = blockIdx.x;
    if (b < 3072) {
        const float* wr = (b < 2304) ? qkv_w + (size_t)b * 768
                                     : out_w + (size_t)(b - 2304) * 768;
        float ss = 0.f;
        for (int c = threadIdx.x; c < 768; c += 256) { float v = wr[c]; ss += v * v; }
        for (int m = 32; m; m >>= 1) ss += __shfl_xor(ss, m, 64);
        if ((threadIdx.x & 63) == 0) red[threadIdx.x >> 6] = ss;
        __syncthreads();
        float inv = 1.0f / (sqrtf(red[0] + red[1] + red[2] + red[3]) + kEPS);
        bf16_t* wo = wn_all + (size_t)b * 768;
        for (int c = threadIdx.x; c < 768; c += 256) wo[c] = (bf16_t)(wr[c] * inv);
    } else {
        int tok = b - 3072;               // 0..8191
        const float* xr = x + (size_t)tok * 768;
        float ss = 0.f;
        for (int c = threadIdx.x; c < 768; c += 256) { float v = xr[c]; ss += v * v; }
        for (int m = 32; m; m >>= 1) ss += __shfl_xor(ss, m, 64);
        if ((threadIdx.x & 63) == 0) red[threadIdx.x >> 6] = ss;
        __syncthreads();
        float tot = red[0] + red[1] + red[2] + red[3];
        if (threadIdx.x == 0) mag[tok] = sqrtf(tot) * 0.036084391824352f;  // 1/sqrt(768)
        bf16_t* xo = xb + (size_t)tok * 768;
        for (int c = threadIdx.x; c < 768; c += 256) xo[c] = (bf16_t)xr[c];
    }
}

// ---------------------------------------------------------------------------
// 3) GEMM1: qkv = xb(8192x768) @ wn^T(2304x768).  128x128 tile, BK=32,
//    distance-2 register prefetch with NAMED registers. Lane-order LDS.
//    Epilogue: q/k per-head normalize (q also *kC) -> qkvh; v (p==2)
//    transposed via LDS to vT (pi-permuted columns).
// ---------------------------------------------------------------------------
__global__ __launch_bounds__(256, 2) void gemm_qkv_kernel(const bf16_t* __restrict__ A,
                                                          const bf16_t* __restrict__ Bw,
                                                          bf16_t* __restrict__ qkvh,
                                                          bf16_t* __restrict__ vT) {
    __shared__ __align__(16) bf16_t sm[8704];   // As 4096 | Bs 4096; reused 64x136 for v-transpose
    bf16_t* As = sm;
    bf16_t* Bs = sm + 4096;

    const int m0 = blockIdx.x * 128;
    const int n0 = blockIdx.y * 128;
    const int tid = threadIdx.x;
    const int wave = tid >> 6, lane = tid & 63;
    const int quad = lane >> 4, l16 = lane & 15;
    const int wr = (wave >> 1) * 64, wc = (wave & 1) * 64;
    const int srow = lane & 15, schunk = lane >> 4;   // staging lane map

    floatx4 acc[4][4];
    for (int i = 0; i < 4; i++)
        for (int j = 0; j < 4; j++) acc[i][j] = (floatx4){0.f, 0.f, 0.f, 0.f};

    const bf16_t* aptr0 = A  + (size_t)(m0 + wave * 32 + srow) * 768 + schunk * 8;
    const bf16_t* bptr0 = Bw + (size_t)(n0 + wave * 32 + srow) * 768 + schunk * 8;
    const int abase = wave * 1024;                    // per-wave region: 2 x 512

    // two prefetch sets, NAMED registers (arrays spilled in R9)
    uint4 aA0, aA1, bA0, bA1, aB0, aB1, bB0, bB1;

    aA0 = *(const uint4*)(aptr0 + 0);
    aA1 = *(const uint4*)(aptr0 + 0 + 16 * 768);
    bA0 = *(const uint4*)(bptr0 + 0);
    bA1 = *(const uint4*)(bptr0 + 0 + 16 * 768);
    aB0 = *(const uint4*)(aptr0 + 32);
    aB1 = *(const uint4*)(aptr0 + 32 + 16 * 768);
    bB0 = *(const uint4*)(bptr0 + 32);
    bB1 = *(const uint4*)(bptr0 + 32 + 16 * 768);

    auto compute = [&]() {
        bf16x8 af[4], bfr[4];
#pragma unroll
        for (int i = 0; i < 4; i++)
            af[i] = *(const bf16x8*)&As[((wr >> 4) + i) * 512 + quad * 128 + l16 * 8];
#pragma unroll
        for (int j = 0; j < 4; j++)
            bfr[j] = *(const bf16x8*)&Bs[((wc >> 4) + j) * 512 + quad * 128 + l16 * 8];
#pragma unroll
        for (int i = 0; i < 4; i++)
#pragma unroll
            for (int j = 0; j < 4; j++) acc[i][j] = MFMA16x16x32(af[i], bfr[j], acc[i][j]);
    };

    for (int u = 0; u < 12; ++u) {
        // even iteration: consume set A, refill A for k=(2u+2)*32
        __syncthreads();
        *(uint4*)&As[abase + lane * 8]       = aA0;
        *(uint4*)&As[abase + 512 + lane * 8] = aA1;
        *(uint4*)&Bs[abase + lane * 8]       = bA0;
        *(uint4*)&Bs[abase + 512 + lane * 8] = bA1;
        if (u < 11) {
            int k0 = (2 * u + 2) * 32;
            aA0 = *(const uint4*)(aptr0 + k0);
            aA1 = *(const uint4*)(aptr0 + k0 + 16 * 768);
            bA0 = *(const uint4*)(bptr0 + k0);
            bA1 = *(const uint4*)(bptr0 + k0 + 16 * 768);
        }
        __syncthreads();
        compute();

        // odd iteration: consume set B, refill B for k=(2u+3)*32
        __syncthreads();
        *(uint4*)&As[abase + lane * 8]       = aB0;
        *(uint4*)&As[abase + 512 + lane * 8] = aB1;
        *(uint4*)&Bs[abase + lane * 8]       = bB0;
        *(uint4*)&Bs[abase + 512 + lane * 8] = bB1;
        if (u < 11) {
            int k0 = (2 * u + 3) * 32;
            aB0 = *(const uint4*)(aptr0 + k0);
            aB1 = *(const uint4*)(aptr0 + k0 + 16 * 768);
            bB0 = *(const uint4*)(bptr0 + k0);
            bB1 = *(const uint4*)(bptr0 + k0 + 16 * 768);
        }
        __syncthreads();
        compute();
    }

    const int p = n0 / 768;        // block-uniform (768 % 128 == 0)
    const int bat = m0 >> 11, t0 = m0 & 2047;

    if (p < 2) {
        // ---- q/k: fused per-head normalize, scatter to qkvh ----
        const int h = ((n0 + wc) - p * 768) >> 6;
        const float base = (p == 0) ? kC * 8.0f : 8.0f;
        for (int i = 0; i < 4; i++)
            for (int r = 0; r < 4; r++) {
                float vals[4], ss = 0.f;
                for (int j = 0; j < 4; j++) { float v = acc[i][j][r]; vals[j] = v; ss += v * v; }
                ss += __shfl_xor(ss, 1, 64);
                ss += __shfl_xor(ss, 2, 64);
                ss += __shfl_xor(ss, 4, 64);
                ss += __shfl_xor(ss, 8, 64);
                float scale = base / (sqrtf(ss) + kEPS);
                int m = m0 + wr + i * 16 + quad * 4 + r;
                int t = m & 2047;
                bf16_t* dst = qkvh + ((((size_t)p * 4 + bat) * 12 + h) * 2048 + t) * 64;
                for (int j = 0; j < 4; j++) dst[j * 16 + l16] = (bf16_t)(vals[j] * scale);
            }
    } else {
        // ---- v: transpose via LDS, write vT[(bh)*64+d][t] pi-permuted ----
        __syncthreads();                         // everyone done with As/Bs
        const int h0 = (n0 - 1536) >> 6;         // block head base (2 heads/block)
        for (int hh = 0; hh < 2; hh++) {
            if ((wc >> 6) == hh) {
                for (int i = 0; i < 4; i++)
                    for (int r = 0; r < 4; r++) {
                        int tl = wr + i * 16 + quad * 4 + r;
                        for (int j = 0; j < 4; j++)
                            sm[(j * 16 + l16) * 136 + tl] = (bf16_t)acc[i][j][r];
                    }
            }
            __syncthreads();
            bf16_t* dst = vT + ((size_t)(bat * 12 + h0 + hh) * 64) * 2048 + t0;
            for (int u = tid; u < 1024; u += 256) {
                int d = u >> 4, c = u & 15;
                bf16_t tmp[8];
#pragma unroll
                for (int q = 0; q < 8; q++) {
                    int sp = c * 8 + q;                      // out position 0..127
                    int q6 = sp & 63;
                    int tl = (sp & 64) + ((q6 & 3) << 4) + (q6 >> 2);   // pi_inv
                    tmp[q] = sm[d * 136 + tl];
                }
                *(uint4*)&dst[(size_t)d * 2048 + c * 8] = *(uint4*)tmp;
            }
            __syncthreads();
        }
    }
}

// ---------------------------------------------------------------------------
// 6) sigmoid attention, fused per-head output normalize + mag rescale.
//    grid (48, 16): x = head (XCD-affine), y = q-tile. 512 thr = 8 waves x
//    16 q-rows. s-tile 64, dbuf K/V, one barrier per s-tile. (R5 exact —
//    best of the R5-R8 structural sweep; dependency-chain floor ~77us.)
// ---------------------------------------------------------------------------
__global__ __launch_bounds__(512, 6) void attn_kernel(const bf16_t* __restrict__ qkvh,
                                                      const bf16_t* __restrict__ vT,
                                                      const float* __restrict__ mag,
                                                      bf16_t* __restrict__ y) {
    __shared__ bf16_t QP[128 * 64];          // Q tile, then reused as Ps
    __shared__ bf16_t KV[2][2][64 * 64];     // [buf][0=K,1=V(pi-order)]

    const int bh = blockIdx.x, bat = bh / 12, h = bh % 12;
    const int m0 = blockIdx.y * 128;
    const bf16_t* qbase = qkvh + (((size_t)bat * 12 + h) * 2048) * 64;            // p=0
    const bf16_t* kbase = qkvh + (((size_t)(4 + bat) * 12 + h) * 2048) * 64;      // p=1
    const bf16_t* vbase = vT + ((size_t)bh * 64) * 2048;

    const int tid = threadIdx.x, wave = tid >> 6, lane = tid & 63;
    const int quad = lane >> 4, l16 = lane & 15;

    // ---- stage Q (swizzled): 1024 uint4 over 512 threads ----
    for (int s = tid; s < 1024; s += 512) {
        int r = s >> 3, blk = s & 7;
        *(uint4*)&QP[r * 64 + ((blk ^ (r & 7)) * 8)] =
            *(const uint4*)&qbase[(size_t)(m0 + r) * 64 + blk * 8];
    }

    // ---- K/V prefetch (1 uint4 of each per thread) ----
    uint4 kr, vr;
    const int slr = tid >> 3, slb = tid & 7;
    auto issue = [&](int s0) {
        kr = *(const uint4*)&kbase[(size_t)(s0 + slr) * 64 + slb * 8];
        vr = *(const uint4*)&vbase[(size_t)slr * 2048 + s0 + slb * 8];
    };
    const int sw = ((slb ^ (slr & 7)) * 8);
    auto commit = [&](int buf) {
        *(uint4*)&KV[buf][0][slr * 64 + sw] = kr;
        *(uint4*)&KV[buf][1][slr * 64 + sw] = vr;
    };

    issue(0);
    __syncthreads();   // Q staged

    // ---- Q fragments -> registers (wave-private rows; QP freed for Ps) ----
    const int qrow = wave * 16 + l16;
    bf16x8 qf0 = *(const bf16x8*)&QP[qrow * 64 + ((quad ^ (l16 & 7)) * 8)];
    bf16x8 qf1 = *(const bf16x8*)&QP[qrow * 64 + (((4 + quad) ^ (l16 & 7)) * 8)];

    commit(0);
    issue(64);
    __syncthreads();   // KV[0] visible; all qf reads done before Ps writes

    floatx4 o[4];
#pragma unroll
    for (int j = 0; j < 4; j++) o[j] = (floatx4){0.f, 0.f, 0.f, 0.f};

    for (int it = 0; it < 32; ++it) {
        const bf16_t* Ks = KV[it & 1][0];
        const bf16_t* Vt = KV[it & 1][1];
        if (it < 31) {
            commit((it + 1) & 1);        // regs loaded one iter ago
            if (it < 30) issue((it + 2) * 64);
        }

        // ---- S = Q.K^T (16 q-rows x 64 s per wave) ----
        floatx4 sacc[4];
#pragma unroll
        for (int j = 0; j < 4; j++) sacc[j] = (floatx4){0.f, 0.f, 0.f, 0.f};
#pragma unroll
        for (int j = 0; j < 4; j++) {
            int row = j * 16 + l16;
            bf16x8 b0 = *(const bf16x8*)&Ks[row * 64 + ((quad ^ (l16 & 7)) * 8)];
            bf16x8 b1 = *(const bf16x8*)&Ks[row * 64 + (((4 + quad) ^ (l16 & 7)) * 8)];
            sacc[j] = MFMA16x16x32(qf0, b0, sacc[j]);
            sacc[j] = MFMA16x16x32(qf1, b1, sacc[j]);
        }

        // ---- sigmoid = rcp(1+exp2(S)) (kC pre-folded into q) -> Ps ----
#pragma unroll
        for (int r = 0; r < 4; r++) {
            int row = wave * 16 + quad * 4 + r;
            bf16x4 pk;
#pragma unroll
            for (int j = 0; j < 4; j++) {
                float t = __builtin_amdgcn_exp2f(sacc[j][r]);
                pk[j] = (bf16_t)__builtin_amdgcn_rcpf(1.0f + t);
            }
            *(bf16x4*)&QP[row * 64 + (((l16 >> 1) ^ (row & 7)) * 8) + (l16 & 1) * 4] = pk;
        }

        // ---- O += P.V (A from QP, B from Vt, both pi-order) ----
        const int prow = wave * 16 + l16;
        bf16x8 af0 = *(const bf16x8*)&QP[prow * 64 + ((quad ^ (l16 & 7)) * 8)];
        bf16x8 af1 = *(const bf16x8*)&QP[prow * 64 + (((4 + quad) ^ (l16 & 7)) * 8)];
#pragma unroll
        for (int j = 0; j < 4; j++) {
            int row = j * 16 + l16;
            bf16x8 b0 = *(const bf16x8*)&Vt[row * 64 + ((quad ^ (l16 & 7)) * 8)];
            bf16x8 b1 = *(const bf16x8*)&Vt[row * 64 + (((4 + quad) ^ (l16 & 7)) * 8)];
            o[j] = MFMA16x16x32(af0, b0, o[j]);
            o[j] = MFMA16x16x32(af1, b1, o[j]);
        }
        __syncthreads();   // one barrier per s-tile
    }

    // ---- epilogue: out = mag * 8 * (kGAIN/sqrt(T)) * o / (||...|| + eps) ----
    const float kfac = kGAIN * 0.02209708691207961f;  // 1.8402/sqrt(2048)
#pragma unroll
    for (int r = 0; r < 4; r++) {
        int t = m0 + wave * 16 + quad * 4 + r;
        float vals[4];
        float ss = 0.f;
#pragma unroll
        for (int j = 0; j < 4; j++) {
            float v = o[j][r] * kfac;
            vals[j] = v;
            ss += v * v;
        }
        for (int msk = 1; msk < 16; msk <<= 1) ss += __shfl_xor(ss, msk, 64);
        float mg = mag[bat * 2048 + t];
        float sc = mg * 8.0f / (sqrtf(ss) + kEPS);
#pragma unroll
        for (int j = 0; j < 4; j++) {
            int d = j * 16 + l16;
            y[((size_t)(bat * 2048 + t)) * 768 + h * 64 + d] = (bf16_t)(vals[j] * sc);
        }
    }
}

// ---------------------------------------------------------------------------
// 7) GEMM2: out = y(8192x768) @ ow^T(768x768) -> fp32, BK=32, distance-2
//    (named prefetch registers, launch_bounds(256,2))
// ---------------------------------------------------------------------------
__global__ __launch_bounds__(256, 2) void gemm_out_kernel(const bf16_t* __restrict__ A,
                                                          const bf16_t* __restrict__ Bw,
                                                          float* __restrict__ out) {
    __shared__ __align__(16) bf16_t sm[8192];
    bf16_t* As = sm;
    bf16_t* Bs = sm + 4096;

    const int m0 = blockIdx.x * 128;
    const int n0 = blockIdx.y * 128;
    const int tid = threadIdx.x;
    const int wave = tid >> 6, lane = tid & 63;
    const int quad = lane >> 4, l16 = lane & 15;
    const int wr = (wave >> 1) * 64, wc = (wave & 1) * 64;
    const int srow = lane & 15, schunk = lane >> 4;

    floatx4 acc[4][4];
    for (int i = 0; i < 4; i++)
        for (int j = 0; j < 4; j++) acc[i][j] = (floatx4){0.f, 0.f, 0.f, 0.f};

    const bf16_t* aptr0 = A  + (size_t)(m0 + wave * 32 + srow) * 768 + schunk * 8;
    const bf16_t* bptr0 = Bw + (size_t)(n0 + wave * 32 + srow) * 768 + schunk * 8;
    const int abase = wave * 1024;

    uint4 aA0, aA1, bA0, bA1, aB0, aB1, bB0, bB1;

    aA0 = *(const uint4*)(aptr0 + 0);
    aA1 = *(const uint4*)(aptr0 + 0 + 16 * 768);
    bA0 = *(const uint4*)(bptr0 + 0);
    bA1 = *(const uint4*)(bptr0 + 0 + 16 * 768);
    aB0 = *(const uint4*)(aptr0 + 32);
    aB1 = *(const uint4*)(aptr0 + 32 + 16 * 768);
    bB0 = *(const uint4*)(bptr0 + 32);
    bB1 = *(const uint4*)(bptr0 + 32 + 16 * 768);

    auto compute = [&]() {
        bf16x8 af[4], bfr[4];
#pragma unroll
        for (int i = 0; i < 4; i++)
            af[i] = *(const bf16x8*)&As[((wr >> 4) + i) * 512 + quad * 128 + l16 * 8];
#pragma unroll
        for (int j = 0; j < 4; j++)
            bfr[j] = *(const bf16x8*)&Bs[((wc >> 4) + j) * 512 + quad * 128 + l16 * 8];
#pragma unroll
        for (int i = 0; i < 4; i++)
#pragma unroll
            for (int j = 0; j < 4; j++) acc[i][j] = MFMA16x16x32(af[i], bfr[j], acc[i][j]);
    };

    for (int u = 0; u < 12; ++u) {
        __syncthreads();
        *(uint4*)&As[abase + lane * 8]       = aA0;
        *(uint4*)&As[abase + 512 + lane * 8] = aA1;
        *(uint4*)&Bs[abase + lane * 8]       = bA0;
        *(uint4*)&Bs[abase + 512 + lane * 8] = bA1;
        if (u < 11) {
            int k0 = (2 * u + 2) * 32;
            aA0 = *(const uint4*)(aptr0 + k0);
            aA1 = *(const uint4*)(aptr0 + k0 + 16 * 768);
            bA0 = *(const uint4*)(bptr0 + k0);
            bA1 = *(const uint4*)(bptr0 + k0 + 16 * 768);
        }
        __syncthreads();
        compute();

        __syncthreads();
        *(uint4*)&As[abase + lane * 8]       = aB0;
        *(uint4*)&As[abase + 512 + lane * 8] = aB1;
        *(uint4*)&Bs[abase + lane * 8]       = bB0;
        *(uint4*)&Bs[abase + 512 + lane * 8] = bB1;
        if (u < 11) {
            int k0 = (2 * u + 3) * 32;
            aB0 = *(const uint4*)(aptr0 + k0);
            aB1 = *(const uint4*)(aptr0 + k0 + 16 * 768);
            bB0 = *(const uint4*)(bptr0 + k0);
            bB1 = *(const uint4*)(bptr0 + k0 + 16 * 768);
        }
        __syncthreads();
        compute();
    }

    for (int i = 0; i < 4; i++)
        for (int j = 0; j < 4; j++) {
            int n = n0 + wc + j * 16 + l16;
            for (int r = 0; r < 4; r++) {
                int m = m0 + wr + i * 16 + quad * 4 + r;
                out[(size_t)m * 768 + n] = acc[i][j][r];
            }
        }
}

// ---------------------------------------------------------------------------
extern "C" void kernel_launch(void* const* d_in, const int* in_sizes, int n_in,
                              void* d_out, int out_size, void* d_ws, size_t ws_size,
                              hipStream_t stream) {
    const float* x     = (const float*)d_in[0];   // (4,2048,768)
    const float* qkv_w = (const float*)d_in[1];   // (2304,768)
    const float* out_w = (const float*)d_in[2];   // (768,768)
    float* out = (float*)d_out;

    char* ws = (char*)d_ws;
    bf16_t* wn_all = (bf16_t*)(ws + 0);          //  4,718,592  (3072x768 bf16: qkv_w rows then out_w rows)
    bf16_t* xb     = (bf16_t*)(ws + 4718592);    // 12,582,912  (8192x768 bf16)
    float*  mag    = (float*) (ws + 17301504);   //     32,768  (8192 fp32)
    bf16_t* qkvh   = (bf16_t*)(ws + 17334272);   // 25,165,824  (2x4x12x2048x64 bf16: q,k)
    bf16_t* vT     = (bf16_t*)(ws + 42500096);   // 12,582,912  (48x64x2048 bf16, pi-permuted cols)
    bf16_t* y      = (bf16_t*)(ws + 55083008);   // 12,582,912  (8192x768 bf16)
    // total 67,665,920 bytes

    bf16_t* ow = wn_all + (size_t)2304 * 768;

    prep_kernel<<<11264, 256, 0, stream>>>(x, qkv_w, out_w, wn_all, xb, mag);
    gemm_qkv_kernel<<<dim3(64, 18), 256, 0, stream>>>(xb, wn_all, qkvh, vT);
    attn_kernel<<<dim3(48, 16), 512, 0, stream>>>(qkvh, vT, mag, y);
    gemm_out_kernel<<<dim3(64, 6), 256, 0, stream>>>(y, ow, out);
}

// Round 11
// 241.152 us; speedup vs baseline: 1.5584x; 1.0017x over previous
//
#include <hip/hip_runtime.h>
#include <hip/hip_bf16.h>

// Attention_4363686773373: sigmoid attention block, all-bf16 MFMA pipeline.
// B=4 T=2048 D=768 H=12 HD=64.  Output fp32.
// R11: R10-exact pipeline; attn micro-ops only:
//  (1) sacc zero-init via MFMA C-operand (kills 16 v_mov/lane-iter),
//  (2) packed f32->bf16 converts (v_cvt_pk_bf16_f32) in the P-pack.
// GEMMs: distance-2 named-register prefetch, launch_bounds(256,2) (R10).

typedef __bf16 bf16_t;
typedef __bf16 bf16x8 __attribute__((ext_vector_type(8)));
typedef __bf16 bf16x4 __attribute__((ext_vector_type(4)));
typedef __bf16 bf16x2 __attribute__((ext_vector_type(2)));
typedef float floatx4 __attribute__((ext_vector_type(4)));

#define MFMA16x16x32(a, b, c) __builtin_amdgcn_mfma_f32_16x16x32_bf16((a), (b), (c), 0, 0, 0)

static constexpr float kEPS  = 1e-4f;
static constexpr float kGAIN = 1.8402f;
static constexpr float kC    = -0.18033688011112042f;   // -0.125 * log2(e)

#if __has_builtin(__builtin_amdgcn_cvt_pk_bf16_f32)
__device__ __forceinline__ bf16x2 pk_bf16(float a, float b) {
    return __builtin_amdgcn_cvt_pk_bf16_f32(a, b);
}
#else
__device__ __forceinline__ bf16x2 pk_bf16(float a, float b) {
    bf16x2 r; r[0] = (bf16_t)a; r[1] = (bf16_t)b; return r;
}
#endif

// ---------------------------------------------------------------------------
// 1) merged preprocessing:
//    blocks [0,3072): row-normalize [qkv_w ; out_w] rows -> bf16
//    blocks [3072,11264): x -> bf16 + per-token magnitude ||x||/sqrt(D)
// ---------------------------------------------------------------------------
__global__ __launch_bounds__(256) void prep_kernel(const float* __restrict__ x,
                                                   const float* __restrict__ qkv_w,
                                                   const float* __restrict__ out_w,
                                                   bf16_t* __restrict__ wn_all,
                                                   bf16_t* __restrict__ xb,
                                                   float* __restrict__ mag) {
    __shared__ float red[4];
    int b = blockIdx.x;
    if (b < 3072) {
        const float* wr = (b < 2304) ? qkv_w + (size_t)b * 768
                                     : out_w + (size_t)(b - 2304) * 768;
        float ss = 0.f;
        for (int c = threadIdx.x; c < 768; c += 256) { float v = wr[c]; ss += v * v; }
        for (int m = 32; m; m >>= 1) ss += __shfl_xor(ss, m, 64);
        if ((threadIdx.x & 63) == 0) red[threadIdx.x >> 6] = ss;
        __syncthreads();
        float inv = 1.0f / (sqrtf(red[0] + red[1] + red[2] + red[3]) + kEPS);
        bf16_t* wo = wn_all + (size_t)b * 768;
        for (int c = threadIdx.x; c < 768; c += 256) wo[c] = (bf16_t)(wr[c] * inv);
    } else {
        int tok = b - 3072;               // 0..8191
        const float* xr = x + (size_t)tok * 768;
        float ss = 0.f;
        for (int c = threadIdx.x; c < 768; c += 256) { float v = xr[c]; ss += v * v; }
        for (int m = 32; m; m >>= 1) ss += __shfl_xor(ss, m, 64);
        if ((threadIdx.x & 63) == 0) red[threadIdx.x >> 6] = ss;
        __syncthreads();
        float tot = red[0] + red[1] + red[2] + red[3];
        if (threadIdx.x == 0) mag[tok] = sqrtf(tot) * 0.036084391824352f;  // 1/sqrt(768)
        bf16_t* xo = xb + (size_t)tok * 768;
        for (int c = threadIdx.x; c < 768; c += 256) xo[c] = (bf16_t)xr[c];
    }
}

// ---------------------------------------------------------------------------
// 3) GEMM1: qkv = xb(8192x768) @ wn^T(2304x768).  128x128 tile, BK=32,
//    distance-2 register prefetch with NAMED registers. Lane-order LDS.
//    Epilogue: q/k per-head normalize (q also *kC) -> qkvh; v (p==2)
//    transposed via LDS to vT (pi-permuted columns).
// ---------------------------------------------------------------------------
__global__ __launch_bounds__(256, 2) void gemm_qkv_kernel(const bf16_t* __restrict__ A,
                                                          const bf16_t* __restrict__ Bw,
                                                          bf16_t* __restrict__ qkvh,
                                                          bf16_t* __restrict__ vT) {
    __shared__ __align__(16) bf16_t sm[8704];   // As 4096 | Bs 4096; reused 64x136 for v-transpose
    bf16_t* As = sm;
    bf16_t* Bs = sm + 4096;

    const int m0 = blockIdx.x * 128;
    const int n0 = blockIdx.y * 128;
    const int tid = threadIdx.x;
    const int wave = tid >> 6, lane = tid & 63;
    const int quad = lane >> 4, l16 = lane & 15;
    const int wr = (wave >> 1) * 64, wc = (wave & 1) * 64;
    const int srow = lane & 15, schunk = lane >> 4;   // staging lane map

    floatx4 acc[4][4];
    for (int i = 0; i < 4; i++)
        for (int j = 0; j < 4; j++) acc[i][j] = (floatx4){0.f, 0.f, 0.f, 0.f};

    const bf16_t* aptr0 = A  + (size_t)(m0 + wave * 32 + srow) * 768 + schunk * 8;
    const bf16_t* bptr0 = Bw + (size_t)(n0 + wave * 32 + srow) * 768 + schunk * 8;
    const int abase = wave * 1024;                    // per-wave region: 2 x 512

    // two prefetch sets, NAMED registers (arrays spilled in R9)
    uint4 aA0, aA1, bA0, bA1, aB0, aB1, bB0, bB1;

    aA0 = *(const uint4*)(aptr0 + 0);
    aA1 = *(const uint4*)(aptr0 + 0 + 16 * 768);
    bA0 = *(const uint4*)(bptr0 + 0);
    bA1 = *(const uint4*)(bptr0 + 0 + 16 * 768);
    aB0 = *(const uint4*)(aptr0 + 32);
    aB1 = *(const uint4*)(aptr0 + 32 + 16 * 768);
    bB0 = *(const uint4*)(bptr0 + 32);
    bB1 = *(const uint4*)(bptr0 + 32 + 16 * 768);

    auto compute = [&]() {
        bf16x8 af[4], bfr[4];
#pragma unroll
        for (int i = 0; i < 4; i++)
            af[i] = *(const bf16x8*)&As[((wr >> 4) + i) * 512 + quad * 128 + l16 * 8];
#pragma unroll
        for (int j = 0; j < 4; j++)
            bfr[j] = *(const bf16x8*)&Bs[((wc >> 4) + j) * 512 + quad * 128 + l16 * 8];
#pragma unroll
        for (int i = 0; i < 4; i++)
#pragma unroll
            for (int j = 0; j < 4; j++) acc[i][j] = MFMA16x16x32(af[i], bfr[j], acc[i][j]);
    };

    for (int u = 0; u < 12; ++u) {
        // even iteration: consume set A, refill A for k=(2u+2)*32
        __syncthreads();
        *(uint4*)&As[abase + lane * 8]       = aA0;
        *(uint4*)&As[abase + 512 + lane * 8] = aA1;
        *(uint4*)&Bs[abase + lane * 8]       = bA0;
        *(uint4*)&Bs[abase + 512 + lane * 8] = bA1;
        if (u < 11) {
            int k0 = (2 * u + 2) * 32;
            aA0 = *(const uint4*)(aptr0 + k0);
            aA1 = *(const uint4*)(aptr0 + k0 + 16 * 768);
            bA0 = *(const uint4*)(bptr0 + k0);
            bA1 = *(const uint4*)(bptr0 + k0 + 16 * 768);
        }
        __syncthreads();
        compute();

        // odd iteration: consume set B, refill B for k=(2u+3)*32
        __syncthreads();
        *(uint4*)&As[abase + lane * 8]       = aB0;
        *(uint4*)&As[abase + 512 + lane * 8] = aB1;
        *(uint4*)&Bs[abase + lane * 8]       = bB0;
        *(uint4*)&Bs[abase + 512 + lane * 8] = bB1;
        if (u < 11) {
            int k0 = (2 * u + 3) * 32;
            aB0 = *(const uint4*)(aptr0 + k0);
            aB1 = *(const uint4*)(aptr0 + k0 + 16 * 768);
            bB0 = *(const uint4*)(bptr0 + k0);
            bB1 = *(const uint4*)(bptr0 + k0 + 16 * 768);
        }
        __syncthreads();
        compute();
    }

    const int p = n0 / 768;        // block-uniform (768 % 128 == 0)
    const int bat = m0 >> 11, t0 = m0 & 2047;

    if (p < 2) {
        // ---- q/k: fused per-head normalize, scatter to qkvh ----
        const int h = ((n0 + wc) - p * 768) >> 6;
        const float base = (p == 0) ? kC * 8.0f : 8.0f;
        for (int i = 0; i < 4; i++)
            for (int r = 0; r < 4; r++) {
                float vals[4], ss = 0.f;
                for (int j = 0; j < 4; j++) { float v = acc[i][j][r]; vals[j] = v; ss += v * v; }
                ss += __shfl_xor(ss, 1, 64);
                ss += __shfl_xor(ss, 2, 64);
                ss += __shfl_xor(ss, 4, 64);
                ss += __shfl_xor(ss, 8, 64);
                float scale = base / (sqrtf(ss) + kEPS);
                int m = m0 + wr + i * 16 + quad * 4 + r;
                int t = m & 2047;
                bf16_t* dst = qkvh + ((((size_t)p * 4 + bat) * 12 + h) * 2048 + t) * 64;
                for (int j = 0; j < 4; j++) dst[j * 16 + l16] = (bf16_t)(vals[j] * scale);
            }
    } else {
        // ---- v: transpose via LDS, write vT[(bh)*64+d][t] pi-permuted ----
        __syncthreads();                         // everyone done with As/Bs
        const int h0 = (n0 - 1536) >> 6;         // block head base (2 heads/block)
        for (int hh = 0; hh < 2; hh++) {
            if ((wc >> 6) == hh) {
                for (int i = 0; i < 4; i++)
                    for (int r = 0; r < 4; r++) {
                        int tl = wr + i * 16 + quad * 4 + r;
                        for (int j = 0; j < 4; j++)
                            sm[(j * 16 + l16) * 136 + tl] = (bf16_t)acc[i][j][r];
                    }
            }
            __syncthreads();
            bf16_t* dst = vT + ((size_t)(bat * 12 + h0 + hh) * 64) * 2048 + t0;
            for (int u = tid; u < 1024; u += 256) {
                int d = u >> 4, c = u & 15;
                bf16_t tmp[8];
#pragma unroll
                for (int q = 0; q < 8; q++) {
                    int sp = c * 8 + q;                      // out position 0..127
                    int q6 = sp & 63;
                    int tl = (sp & 64) + ((q6 & 3) << 4) + (q6 >> 2);   // pi_inv
                    tmp[q] = sm[d * 136 + tl];
                }
                *(uint4*)&dst[(size_t)d * 2048 + c * 8] = *(uint4*)tmp;
            }
            __syncthreads();
        }
    }
}

// ---------------------------------------------------------------------------
// 6) sigmoid attention, fused per-head output normalize + mag rescale.
//    grid (48, 16): x = head (XCD-affine), y = q-tile. 512 thr = 8 waves x
//    16 q-rows. s-tile 64, dbuf K/V, one barrier per s-tile.
//    R11: sacc zero-init via MFMA C-operand; packed bf16 converts in P-pack.
// ---------------------------------------------------------------------------
__global__ __launch_bounds__(512, 6) void attn_kernel(const bf16_t* __restrict__ qkvh,
                                                      const bf16_t* __restrict__ vT,
                                                      const float* __restrict__ mag,
                                                      bf16_t* __restrict__ y) {
    __shared__ bf16_t QP[128 * 64];          // Q tile, then reused as Ps
    __shared__ bf16_t KV[2][2][64 * 64];     // [buf][0=K,1=V(pi-order)]

    const int bh = blockIdx.x, bat = bh / 12, h = bh % 12;
    const int m0 = blockIdx.y * 128;
    const bf16_t* qbase = qkvh + (((size_t)bat * 12 + h) * 2048) * 64;            // p=0
    const bf16_t* kbase = qkvh + (((size_t)(4 + bat) * 12 + h) * 2048) * 64;      // p=1
    const bf16_t* vbase = vT + ((size_t)bh * 64) * 2048;

    const int tid = threadIdx.x, wave = tid >> 6, lane = tid & 63;
    const int quad = lane >> 4, l16 = lane & 15;

    // ---- stage Q (swizzled): 1024 uint4 over 512 threads ----
    for (int s = tid; s < 1024; s += 512) {
        int r = s >> 3, blk = s & 7;
        *(uint4*)&QP[r * 64 + ((blk ^ (r & 7)) * 8)] =
            *(const uint4*)&qbase[(size_t)(m0 + r) * 64 + blk * 8];
    }

    // ---- K/V prefetch (1 uint4 of each per thread) ----
    uint4 kr, vr;
    const int slr = tid >> 3, slb = tid & 7;
    auto issue = [&](int s0) {
        kr = *(const uint4*)&kbase[(size_t)(s0 + slr) * 64 + slb * 8];
        vr = *(const uint4*)&vbase[(size_t)slr * 2048 + s0 + slb * 8];
    };
    const int sw = ((slb ^ (slr & 7)) * 8);
    auto commit = [&](int buf) {
        *(uint4*)&KV[buf][0][slr * 64 + sw] = kr;
        *(uint4*)&KV[buf][1][slr * 64 + sw] = vr;
    };

    issue(0);
    __syncthreads();   // Q staged

    // ---- Q fragments -> registers (wave-private rows; QP freed for Ps) ----
    const int qrow = wave * 16 + l16;
    bf16x8 qf0 = *(const bf16x8*)&QP[qrow * 64 + ((quad ^ (l16 & 7)) * 8)];
    bf16x8 qf1 = *(const bf16x8*)&QP[qrow * 64 + (((4 + quad) ^ (l16 & 7)) * 8)];

    commit(0);
    issue(64);
    __syncthreads();   // KV[0] visible; all qf reads done before Ps writes

    const floatx4 fz = (floatx4){0.f, 0.f, 0.f, 0.f};   // loop-invariant zero C

    floatx4 o[4];
#pragma unroll
    for (int j = 0; j < 4; j++) o[j] = fz;

    for (int it = 0; it < 32; ++it) {
        const bf16_t* Ks = KV[it & 1][0];
        const bf16_t* Vt = KV[it & 1][1];
        if (it < 31) {
            commit((it + 1) & 1);        // regs loaded one iter ago
            if (it < 30) issue((it + 2) * 64);
        }

        // ---- S = Q.K^T (16 q-rows x 64 s per wave); C=fz kills per-iter movs
        floatx4 sacc[4];
#pragma unroll
        for (int j = 0; j < 4; j++) {
            int row = j * 16 + l16;
            bf16x8 b0 = *(const bf16x8*)&Ks[row * 64 + ((quad ^ (l16 & 7)) * 8)];
            bf16x8 b1 = *(const bf16x8*)&Ks[row * 64 + (((4 + quad) ^ (l16 & 7)) * 8)];
            sacc[j] = MFMA16x16x32(qf0, b0, fz);
            sacc[j] = MFMA16x16x32(qf1, b1, sacc[j]);
        }

        // ---- sigmoid = rcp(1+exp2(S)) (kC pre-folded into q) -> Ps ----
#pragma unroll
        for (int r = 0; r < 4; r++) {
            int row = wave * 16 + quad * 4 + r;
            float s0 = __builtin_amdgcn_rcpf(1.0f + __builtin_amdgcn_exp2f(sacc[0][r]));
            float s1 = __builtin_amdgcn_rcpf(1.0f + __builtin_amdgcn_exp2f(sacc[1][r]));
            float s2 = __builtin_amdgcn_rcpf(1.0f + __builtin_amdgcn_exp2f(sacc[2][r]));
            float s3 = __builtin_amdgcn_rcpf(1.0f + __builtin_amdgcn_exp2f(sacc[3][r]));
            bf16x2 lo = pk_bf16(s0, s1);
            bf16x2 hi = pk_bf16(s2, s3);
            bf16x4 pk = __builtin_shufflevector(lo, hi, 0, 1, 2, 3);
            *(bf16x4*)&QP[row * 64 + (((l16 >> 1) ^ (row & 7)) * 8) + (l16 & 1) * 4] = pk;
        }

        // ---- O += P.V (A from QP, B from Vt, both pi-order) ----
        const int prow = wave * 16 + l16;
        bf16x8 af0 = *(const bf16x8*)&QP[prow * 64 + ((quad ^ (l16 & 7)) * 8)];
        bf16x8 af1 = *(const bf16x8*)&QP[prow * 64 + (((4 + quad) ^ (l16 & 7)) * 8)];
#pragma unroll
        for (int j = 0; j < 4; j++) {
            int row = j * 16 + l16;
            bf16x8 b0 = *(const bf16x8*)&Vt[row * 64 + ((quad ^ (l16 & 7)) * 8)];
            bf16x8 b1 = *(const bf16x8*)&Vt[row * 64 + (((4 + quad) ^ (l16 & 7)) * 8)];
            o[j] = MFMA16x16x32(af0, b0, o[j]);
            o[j] = MFMA16x16x32(af1, b1, o[j]);
        }
        __syncthreads();   // one barrier per s-tile
    }

    // ---- epilogue: out = mag * 8 * (kGAIN/sqrt(T)) * o / (||...|| + eps) ----
    const float kfac = kGAIN * 0.02209708691207961f;  // 1.8402/sqrt(2048)
#pragma unroll
    for (int r = 0; r < 4; r++) {
        int t = m0 + wave * 16 + quad * 4 + r;
        float vals[4];
        float ss = 0.f;
#pragma unroll
        for (int j = 0; j < 4; j++) {
            float v = o[j][r] * kfac;
            vals[j] = v;
            ss += v * v;
        }
        for (int msk = 1; msk < 16; msk <<= 1) ss += __shfl_xor(ss, msk, 64);
        float mg = mag[bat * 2048 + t];
        float sc = mg * 8.0f / (sqrtf(ss) + kEPS);
#pragma unroll
        for (int j = 0; j < 4; j++) {
            int d = j * 16 + l16;
            y[((size_t)(bat * 2048 + t)) * 768 + h * 64 + d] = (bf16_t)(vals[j] * sc);
        }
    }
}

// ---------------------------------------------------------------------------
// 7) GEMM2: out = y(8192x768) @ ow^T(768x768) -> fp32, BK=32, distance-2
//    (named prefetch registers, launch_bounds(256,2))
// ---------------------------------------------------------------------------
__global__ __launch_bounds__(256, 2) void gemm_out_kernel(const bf16_t* __restrict__ A,
                                                          const bf16_t* __restrict__ Bw,
                                                          float* __restrict__ out) {
    __shared__ __align__(16) bf16_t sm[8192];
    bf16_t* As = sm;
    bf16_t* Bs = sm + 4096;

    const int m0 = blockIdx.x * 128;
    const int n0 = blockIdx.y * 128;
    const int tid = threadIdx.x;
    const int wave = tid >> 6, lane = tid & 63;
    const int quad = lane >> 4, l16 = lane & 15;
    const int wr = (wave >> 1) * 64, wc = (wave & 1) * 64;
    const int srow = lane & 15, schunk = lane >> 4;

    floatx4 acc[4][4];
    for (int i = 0; i < 4; i++)
        for (int j = 0; j < 4; j++) acc[i][j] = (floatx4){0.f, 0.f, 0.f, 0.f};

    const bf16_t* aptr0 = A  + (size_t)(m0 + wave * 32 + srow) * 768 + schunk * 8;
    const bf16_t* bptr0 = Bw + (size_t)(n0 + wave * 32 + srow) * 768 + schunk * 8;
    const int abase = wave * 1024;

    uint4 aA0, aA1, bA0, bA1, aB0, aB1, bB0, bB1;

    aA0 = *(const uint4*)(aptr0 + 0);
    aA1 = *(const uint4*)(aptr0 + 0 + 16 * 768);
    bA0 = *(const uint4*)(bptr0 + 0);
    bA1 = *(const uint4*)(bptr0 + 0 + 16 * 768);
    aB0 = *(const uint4*)(aptr0 + 32);
    aB1 = *(const uint4*)(aptr0 + 32 + 16 * 768);
    bB0 = *(const uint4*)(bptr0 + 32);
    bB1 = *(const uint4*)(bptr0 + 32 + 16 * 768);

    auto compute = [&]() {
        bf16x8 af[4], bfr[4];
#pragma unroll
        for (int i = 0; i < 4; i++)
            af[i] = *(const bf16x8*)&As[((wr >> 4) + i) * 512 + quad * 128 + l16 * 8];
#pragma unroll
        for (int j = 0; j < 4; j++)
            bfr[j] = *(const bf16x8*)&Bs[((wc >> 4) + j) * 512 + quad * 128 + l16 * 8];
#pragma unroll
        for (int i = 0; i < 4; i++)
#pragma unroll
            for (int j = 0; j < 4; j++) acc[i][j] = MFMA16x16x32(af[i], bfr[j], acc[i][j]);
    };

    for (int u = 0; u < 12; ++u) {
        __syncthreads();
        *(uint4*)&As[abase + lane * 8]       = aA0;
        *(uint4*)&As[abase + 512 + lane * 8] = aA1;
        *(uint4*)&Bs[abase + lane * 8]       = bA0;
        *(uint4*)&Bs[abase + 512 + lane * 8] = bA1;
        if (u < 11) {
            int k0 = (2 * u + 2) * 32;
            aA0 = *(const uint4*)(aptr0 + k0);
            aA1 = *(const uint4*)(aptr0 + k0 + 16 * 768);
            bA0 = *(const uint4*)(bptr0 + k0);
            bA1 = *(const uint4*)(bptr0 + k0 + 16 * 768);
        }
        __syncthreads();
        compute();

        __syncthreads();
        *(uint4*)&As[abase + lane * 8]       = aB0;
        *(uint4*)&As[abase + 512 + lane * 8] = aB1;
        *(uint4*)&Bs[abase + lane * 8]       = bB0;
        *(uint4*)&Bs[abase + 512 + lane * 8] = bB1;
        if (u < 11) {
            int k0 = (2 * u + 3) * 32;
            aB0 = *(const uint4*)(aptr0 + k0);
            aB1 = *(const uint4*)(aptr0 + k0 + 16 * 768);
            bB0 = *(const uint4*)(bptr0 + k0);
            bB1 = *(const uint4*)(bptr0 + k0 + 16 * 768);
        }
        __syncthreads();
        compute();
    }

    for (int i = 0; i < 4; i++)
        for (int j = 0; j < 4; j++) {
            int n = n0 + wc + j * 16 + l16;
            for (int r = 0; r < 4; r++) {
                int m = m0 + wr + i * 16 + quad * 4 + r;
                out[(size_t)m * 768 + n] = acc[i][j][r];
            }
        }
}

// ---------------------------------------------------------------------------
extern "C" void kernel_launch(void* const* d_in, const int* in_sizes, int n_in,
                              void* d_out, int out_size, void* d_ws, size_t ws_size,
                              hipStream_t stream) {
    const float* x     = (const float*)d_in[0];   // (4,2048,768)
    const float* qkv_w = (const float*)d_in[1];   // (2304,768)
    const float* out_w = (const float*)d_in[2];   // (768,768)
    float* out = (float*)d_out;

    char* ws = (char*)d_ws;
    bf16_t* wn_all = (bf16_t*)(ws + 0);          //  4,718,592  (3072x768 bf16: qkv_w rows then out_w rows)
    bf16_t* xb     = (bf16_t*)(ws + 4718592);    // 12,582,912  (8192x768 bf16)
    float*  mag    = (float*) (ws + 17301504);   //     32,768  (8192 fp32)
    bf16_t* qkvh   = (bf16_t*)(ws + 17334272);   // 25,165,824  (2x4x12x2048x64 bf16: q,k)
    bf16_t* vT     = (bf16_t*)(ws + 42500096);   // 12,582,912  (48x64x2048 bf16, pi-permuted cols)
    bf16_t* y      = (bf16_t*)(ws + 55083008);   // 12,582,912  (8192x768 bf16)
    // total 67,665,920 bytes

    bf16_t* ow = wn_all + (size_t)2304 * 768;

    prep_kernel<<<11264, 256, 0, stream>>>(x, qkv_w, out_w, wn_all, xb, mag);
    gemm_qkv_kernel<<<dim3(64, 18), 256, 0, stream>>>(xb, wn_all, qkvh, vT);
    attn_kernel<<<dim3(48, 16), 512, 0, stream>>>(qkvh, vT, mag, y);
    gemm_out_kernel<<<dim3(64, 6), 256, 0, stream>>>(y, ow, out);
}